// Round 2
// baseline (2201.214 us; speedup 1.0000x reference)
//
#include <hip/hip_runtime.h>
#include <hip/hip_bf16.h>
#include <math.h>

// N=200000 nodes, U=100000 users, D=64, L=3, E=3,000,000 per edge list, NLINK=100000.
// Workspace budget: 3 bf16 node buffers (76.8MB) + 2 CSR col (24MB) + aux (~5MB) ~= 106MB.

typedef unsigned short u16;
typedef unsigned int   u32;

__device__ __forceinline__ float bf2f(u16 v) {
    u32 x = ((u32)v) << 16;
    return __builtin_bit_cast(float, x);
}
__device__ __forceinline__ u16 f2bf(float f) {
    u32 x = __builtin_bit_cast(u32, f);
    u32 r = x + 0x7fffu + ((x >> 16) & 1u);   // round-to-nearest-even
    return (u16)(r >> 16);
}
__device__ __forceinline__ float rdlane(float v, int l) {
    int i = __builtin_amdgcn_readlane(__builtin_bit_cast(int, v), l);
    return __builtin_bit_cast(float, i);
}

// ---------------- CSR build ----------------

__global__ void hist_kernel(const int* __restrict__ dst, int e, int* __restrict__ deg) {
    int i = blockIdx.x * blockDim.x + threadIdx.x;
    if (i < e) atomicAdd(&deg[dst[i]], 1);
}

__global__ void invdeg_kernel(const int* __restrict__ degs, const int* __restrict__ degt,
                              float* __restrict__ invs, float* __restrict__ invt, int n) {
    int i = blockIdx.x * blockDim.x + threadIdx.x;
    if (i < n) {
        int ds = degs[i]; invs[i] = 1.0f / (float)(ds > 1 ? ds : 1);
        int dt = degt[i]; invt[i] = 1.0f / (float)(dt > 1 ? dt : 1);
    }
}

__global__ void scan_sums(const int* __restrict__ deg, int n, int* __restrict__ bsums) {
    __shared__ int red[256];
    int tid = threadIdx.x;
    int base = blockIdx.x * 1024 + tid * 4;
    int s = 0;
#pragma unroll
    for (int j = 0; j < 4; ++j)
        if (base + j < n) s += deg[base + j];
    red[tid] = s; __syncthreads();
    for (int off = 128; off > 0; off >>= 1) {
        if (tid < off) red[tid] += red[tid + off];
        __syncthreads();
    }
    if (tid == 0) bsums[blockIdx.x] = red[0];
}

__global__ void scan_bsums(int* bsums, int nb) {
    if (threadIdx.x == 0 && blockIdx.x == 0) {
        int run = 0;
        for (int i = 0; i < nb; ++i) { int v = bsums[i]; bsums[i] = run; run += v; }
    }
}

__global__ void scan_write(const int* __restrict__ deg, int n, const int* __restrict__ bsums,
                           int* __restrict__ rowstart) {
    __shared__ int red[256];
    int tid = threadIdx.x;
    int base = blockIdx.x * 1024 + tid * 4;
    int v[4]; int s = 0;
#pragma unroll
    for (int j = 0; j < 4; ++j) { v[j] = (base + j < n) ? deg[base + j] : 0; s += v[j]; }
    red[tid] = s; __syncthreads();
    for (int off = 1; off < 256; off <<= 1) {
        int t = (tid >= off) ? red[tid - off] : 0;
        __syncthreads();
        red[tid] += t;
        __syncthreads();
    }
    int excl = red[tid] - s + bsums[blockIdx.x];
#pragma unroll
    for (int j = 0; j < 4; ++j) {
        if (base + j < n) { rowstart[base + j] = excl; excl += v[j]; }
    }
}

// Destructive scatter: rs advances to row-end; agg recovers beg = rs_end - deg.
__global__ void scatter_kernel(const int* __restrict__ src, const int* __restrict__ dst, int e,
                               int* __restrict__ rs, int* __restrict__ col) {
    int i = blockIdx.x * blockDim.x + threadIdx.x;
    if (i < e) {
        int d = dst[i];
        int p = atomicAdd(&rs[d], 1);
        col[p] = src[i];
    }
}

// ---------------- mean aggregation ----------------
// One wave per dst node. Half-wave (32 lanes) covers the 64 features (2/lane);
// the two half-waves process alternating edges (2 edges in flight per wave).

template <bool FP32IN>
__global__ __launch_bounds__(256) void agg_kernel(const void* __restrict__ xin,
        const int* __restrict__ rs_end, const int* __restrict__ deg,
        const int* __restrict__ col, const float* __restrict__ invdeg,
        u32* __restrict__ out, int n) {
    int node = blockIdx.x * 4 + (threadIdx.x >> 6);
    if (node >= n) return;
    node = __builtin_amdgcn_readfirstlane(node);
    int lane = threadIdx.x & 63;
    int half = lane >> 5;          // which edge of the pair
    int fl   = lane & 31;          // feature pair index (features 2fl, 2fl+1)
    int dgv = deg[node];
    int beg = rs_end[node] - dgv;
    float a0 = 0.f, a1 = 0.f;
    if (FP32IN) {
        const float2* xf = (const float2*)xin;
        for (int j = half; j < dgv; j += 2) {
            int s = col[beg + j];
            float2 v = xf[s * 32 + fl];
            a0 += v.x; a1 += v.y;
        }
    } else {
        const u32* xb = (const u32*)xin;
        for (int j = half; j < dgv; j += 2) {
            int s = col[beg + j];
            u32 pv = xb[s * 32 + fl];
            a0 += bf2f((u16)pv);
            a1 += bf2f((u16)(pv >> 16));
        }
    }
    a0 += __shfl_xor(a0, 32, 64);
    a1 += __shfl_xor(a1, 32, 64);
    if (half == 0) {
        float inv = invdeg[node];
        u32 o = (u32)f2bf(a0 * inv) | ((u32)f2bf(a1 * inv) << 16);
        out[node * 32 + fl] = o;
    }
}

// ---------------- user mix: user_emb = W[i] @ [sx(u); tx(u)] + b[i] ----------------
__global__ __launch_bounds__(256) void mix_kernel(u16* __restrict__ sbuf, u16* __restrict__ tbuf,
        const float* __restrict__ w, const float* __restrict__ bias, int nu) {
    __shared__ float wT[128 * 65];     // [k][d], stride 65 -> conflict-free r/w
    int tid = threadIdx.x;
    for (int idx = tid; idx < 8192; idx += 256) {
        int d = idx >> 7, k = idx & 127;          // w[d*128+k], coalesced read
        wT[k * 65 + d] = w[idx];
    }
    __syncthreads();
    int lane = tid & 63;
    int u = blockIdx.x * 4 + (tid >> 6);
    if (u < nu) {
        float cs = bf2f(sbuf[u * 64 + lane]);
        float ct = bf2f(tbuf[u * 64 + lane]);
        float acc = bias[lane];
#pragma unroll
        for (int k = 0; k < 64; ++k) acc += wT[k * 65 + lane] * rdlane(cs, k);
#pragma unroll
        for (int k = 0; k < 64; ++k) acc += wT[(64 + k) * 65 + lane] * rdlane(ct, k);
        u16 r = f2bf(acc);
        sbuf[u * 64 + lane] = r;
        tbuf[u * 64 + lane] = r;
    }
}

// ---------------- predictor: per-layer linear accumulation ----------------

__global__ __launch_bounds__(256) void pred0_kernel(const float* __restrict__ emb,
        const int* __restrict__ l0, const int* __restrict__ l1,
        const float* __restrict__ pw, float* __restrict__ acc, int nl) {
    int li = blockIdx.x * 4 + (threadIdx.x >> 6);
    if (li >= nl) return;
    li = __builtin_amdgcn_readfirstlane(li);
    int lane = threadIdx.x & 63;
    int u = l0[li], v = l1[li];
    float s = pw[lane] * emb[u * 64 + lane] + pw[256 + lane] * emb[v * 64 + lane];
#pragma unroll
    for (int off = 32; off > 0; off >>= 1) s += __shfl_xor(s, off, 64);
    if (lane == 0) acc[li] = s;
}

__global__ __launch_bounds__(256) void predl_kernel(const u16* __restrict__ xb,
        const int* __restrict__ l0, const int* __restrict__ l1,
        const float* __restrict__ pw, int ofA, int ofB,
        float* __restrict__ acc, int nl,
        const float* __restrict__ pb, int finalize, float* __restrict__ out) {
    int li = blockIdx.x * 4 + (threadIdx.x >> 6);
    if (li >= nl) return;
    li = __builtin_amdgcn_readfirstlane(li);
    int lane = threadIdx.x & 63;
    int u = l0[li], v = l1[li];
    float s = pw[ofA + lane] * bf2f(xb[u * 64 + lane])
            + pw[ofB + lane] * bf2f(xb[v * 64 + lane]);
#pragma unroll
    for (int off = 32; off > 0; off >>= 1) s += __shfl_xor(s, off, 64);
    if (lane == 0) {
        float t = acc[li] + s;
        if (finalize) {
            t += pb[0];
            t = t > 0.f ? t : 0.01f * t;
            out[li] = 1.f / (1.f + expf(-t));
        } else {
            acc[li] = t;
        }
    }
}

extern "C" void kernel_launch(void* const* d_in, const int* in_sizes, int n_in,
                              void* d_out, int out_size, void* d_ws, size_t ws_size,
                              hipStream_t stream) {
    const int*   se  = (const int*)d_in[0];   // [2,E] src then dst
    const int*   te  = (const int*)d_in[1];
    const int*   lk  = (const int*)d_in[2];   // [2,NLINK]
    const float* emb = (const float*)d_in[3]; // [N,64]
    const float* mw  = (const float*)d_in[4]; // [3,64,128]
    const float* mb  = (const float*)d_in[5]; // [3,64]
    const float* pw  = (const float*)d_in[6]; // [1,512]
    const float* pb  = (const float*)d_in[7]; // [1]
    float* out = (float*)d_out;

    const int E  = in_sizes[0] / 2;
    const int NL = in_sizes[2] / 2;
    const int N  = in_sizes[3] / 64;
    const int U  = 100000;

    char* p = (char*)d_ws;
    auto alloc = [&](size_t bytes) -> char* {
        char* r = p;
        p += (bytes + 255) & ~(size_t)255;
        return r;
    };
    u32*   A     = (u32*)alloc((size_t)N * 32 * 4);   // bf16 node buf (25.6MB)
    u32*   B     = (u32*)alloc((size_t)N * 32 * 4);
    u32*   C     = (u32*)alloc((size_t)N * 32 * 4);
    int*   col_s = (int*)alloc((size_t)E * 4);
    int*   col_t = (int*)alloc((size_t)E * 4);
    int*   deg_s = (int*)alloc((size_t)N * 4);
    int*   deg_t = (int*)alloc((size_t)N * 4);
    int*   rs_s  = (int*)alloc((size_t)N * 4);
    int*   rs_t  = (int*)alloc((size_t)N * 4);
    float* inv_s = (float*)alloc((size_t)N * 4);
    float* inv_t = (float*)alloc((size_t)N * 4);
    float* acc   = (float*)alloc((size_t)NL * 4);
    int*   bsums = (int*)alloc(4096);

    hipMemsetAsync(deg_s, 0, (size_t)N * 4, stream);
    hipMemsetAsync(deg_t, 0, (size_t)N * 4, stream);

    int gE = (E + 255) / 256;
    int gN = (N + 255) / 256;
    hist_kernel<<<gE, 256, 0, stream>>>(se + E, E, deg_s);
    hist_kernel<<<gE, 256, 0, stream>>>(te + E, E, deg_t);
    invdeg_kernel<<<gN, 256, 0, stream>>>(deg_s, deg_t, inv_s, inv_t, N);

    int nb = (N + 1023) / 1024;
    scan_sums<<<nb, 256, 0, stream>>>(deg_s, N, bsums);
    scan_bsums<<<1, 64, 0, stream>>>(bsums, nb);
    scan_write<<<nb, 256, 0, stream>>>(deg_s, N, bsums, rs_s);
    scan_sums<<<nb, 256, 0, stream>>>(deg_t, N, bsums);
    scan_bsums<<<1, 64, 0, stream>>>(bsums, nb);
    scan_write<<<nb, 256, 0, stream>>>(deg_t, N, bsums, rs_t);

    scatter_kernel<<<gE, 256, 0, stream>>>(se, se + E, E, rs_s, col_s);
    scatter_kernel<<<gE, 256, 0, stream>>>(te, te + E, E, rs_t, col_t);

    int gagg  = (N + 3) / 4;
    int gmix  = (U + 3) / 4;
    int gpred = (NL + 3) / 4;

    // layer-0 predictor contribution (fp32 emb)
    pred0_kernel<<<gpred, 256, 0, stream>>>(emb, lk, lk + NL, pw, acc, NL);

    // layer 1: A = agg_s(emb), B = agg_t(emb)
    agg_kernel<true ><<<gagg, 256, 0, stream>>>(emb, rs_s, deg_s, col_s, inv_s, A, N);
    agg_kernel<true ><<<gagg, 256, 0, stream>>>(emb, rs_t, deg_t, col_t, inv_t, B, N);
    mix_kernel<<<gmix, 256, 0, stream>>>((u16*)A, (u16*)B, mw + 0 * 8192, mb + 0 * 64, U);
    predl_kernel<<<gpred, 256, 0, stream>>>((const u16*)A, lk, lk + NL, pw, 64, 320, acc, NL, pb, 0, out);

    // layer 2: C = agg_s(A), A = agg_t(B)   (A's contribution already accumulated)
    agg_kernel<false><<<gagg, 256, 0, stream>>>(A, rs_s, deg_s, col_s, inv_s, C, N);
    agg_kernel<false><<<gagg, 256, 0, stream>>>(B, rs_t, deg_t, col_t, inv_t, A, N);
    mix_kernel<<<gmix, 256, 0, stream>>>((u16*)C, (u16*)A, mw + 1 * 8192, mb + 1 * 64, U);
    predl_kernel<<<gpred, 256, 0, stream>>>((const u16*)C, lk, lk + NL, pw, 128, 384, acc, NL, pb, 0, out);

    // layer 3: B = agg_s(C), C = agg_t(A)
    agg_kernel<false><<<gagg, 256, 0, stream>>>(C, rs_s, deg_s, col_s, inv_s, B, N);
    agg_kernel<false><<<gagg, 256, 0, stream>>>(A, rs_t, deg_t, col_t, inv_t, C, N);
    mix_kernel<<<gmix, 256, 0, stream>>>((u16*)B, (u16*)C, mw + 2 * 8192, mb + 2 * 64, U);
    predl_kernel<<<gpred, 256, 0, stream>>>((const u16*)B, lk, lk + NL, pw, 192, 448, acc, NL, pb, 1, out);
}

// Round 3
// 1289.877 us; speedup vs baseline: 1.7065x; 1.7065x over previous
//
#include <hip/hip_runtime.h>
#include <hip/hip_bf16.h>
#include <math.h>

// N=200000 nodes, U=100000 users, D=64, L=3, E=3,000,000 per edge list, NLINK=100000.
// Workspace: 3 bf16 node bufs (76.8MB) + 2 bin/col (24MB, sorted in place) + aux ~= 103MB.

typedef unsigned short u16;
typedef unsigned int   u32;

#define BSHIFT 9                 // 512 nodes per coarse bucket
#define BWIDTH 512
#define BCAP   8192              // LDS staging per bucket (mean ~7.7K, max ~8.0K)
#define OVF    8                 // register overflow slots (+2048 entries headroom)
#define CHUNK  8192              // edges per binning block

__device__ __forceinline__ float bf2f(u16 v) {
    u32 x = ((u32)v) << 16;
    return __builtin_bit_cast(float, x);
}
__device__ __forceinline__ u16 f2bf(float f) {
    u32 x = __builtin_bit_cast(u32, f);
    u32 r = x + 0x7fffu + ((x >> 16) & 1u);   // round-to-nearest-even
    return (u16)(r >> 16);
}
__device__ __forceinline__ float rdlane(float v, int l) {
    int i = __builtin_amdgcn_readlane(__builtin_bit_cast(int, v), l);
    return __builtin_bit_cast(float, i);
}

// ---------------- CSR build: two-level counting sort ----------------

__global__ __launch_bounds__(256) void bucket_hist(const int* __restrict__ dst, int e,
                                                   int* __restrict__ gcnt) {
    __shared__ int lcnt[BWIDTH];
    int tid = threadIdx.x;
    for (int i = tid; i < BWIDTH; i += 256) lcnt[i] = 0;
    __syncthreads();
    int base = blockIdx.x * CHUNK;
    int end = min(base + CHUNK, e);
    for (int i = base + tid; i < end; i += 256)
        atomicAdd(&lcnt[(u32)dst[i] >> BSHIFT], 1);
    __syncthreads();
    for (int i = tid; i < BWIDTH; i += 256)
        if (lcnt[i]) atomicAdd(&gcnt[i], lcnt[i]);
}

__global__ void bucket_scan(const int* __restrict__ gcnt, int nb, int* __restrict__ bbase,
                            int* __restrict__ cursor, int* __restrict__ rowstart, int n) {
    if (threadIdx.x == 0 && blockIdx.x == 0) {
        int run = 0;
        for (int i = 0; i < nb; ++i) { bbase[i] = run; cursor[i] = run; run += gcnt[i]; }
        bbase[nb] = run;
        rowstart[n] = run;     // sentinel: rowstart[N] = E
    }
}

__global__ __launch_bounds__(256) void bin_kernel(const int* __restrict__ src,
        const int* __restrict__ dst, int e, int* __restrict__ cursor, u32* __restrict__ bin) {
    __shared__ int lcnt[BWIDTH];
    __shared__ int lbase[BWIDTH];
    int tid = threadIdx.x;
    for (int i = tid; i < BWIDTH; i += 256) lcnt[i] = 0;
    __syncthreads();
    int base = blockIdx.x * CHUNK;
    int end = min(base + CHUNK, e);
    for (int i = base + tid; i < end; i += 256)
        atomicAdd(&lcnt[(u32)dst[i] >> BSHIFT], 1);
    __syncthreads();
    for (int i = tid; i < BWIDTH; i += 256) {
        int c = lcnt[i];
        lbase[i] = c ? atomicAdd(&cursor[i], c) : 0;   // bulk segment reservation
        lcnt[i] = 0;
    }
    __syncthreads();
    for (int i = base + tid; i < end; i += 256) {
        int d = dst[i];
        int b = (u32)d >> BSHIFT;
        int pos = lbase[b] + atomicAdd(&lcnt[b], 1);
        bin[pos] = (u32)src[i] | ((u32)(d & (BWIDTH - 1)) << 18);   // src<2^18
    }
}

// one block per bucket: LDS counting sort, writes rowstart, sorts bin IN PLACE into col values
__global__ __launch_bounds__(256) void sort_kernel(u32* __restrict__ bin,
        const int* __restrict__ bbase, int* __restrict__ rowstart, int n) {
    __shared__ u32 ent[BCAP];
    __shared__ int cnt[BWIDTH];
    __shared__ int part[256];
    int b = blockIdx.x;
    int tid = threadIdx.x;
    int beg = bbase[b], end = bbase[b + 1];
    int sz = end - beg;
    for (int i = tid; i < BWIDTH; i += 256) cnt[i] = 0;
    __syncthreads();
    u32 ovf[OVF];
    for (int i = tid; i < sz; i += 256) {
        u32 v = bin[beg + i];
        if (i < BCAP) ent[i] = v;
        else { int k = (i - BCAP) >> 8; if (k < OVF) ovf[k] = v; }
        atomicAdd(&cnt[v >> 18], 1);
    }
    __syncthreads();
    int l0 = tid * 2;
    int c0 = cnt[l0], c1 = cnt[l0 + 1];
    int s = c0 + c1;
    part[tid] = s;
    __syncthreads();
    for (int off = 1; off < 256; off <<= 1) {
        int t = (tid >= off) ? part[tid - off] : 0;
        __syncthreads();
        part[tid] += t;
        __syncthreads();
    }
    int excl = part[tid] - s;
    int node = (b << BSHIFT) + l0;
    if (node < n)     rowstart[node]     = beg + excl;
    if (node + 1 < n) rowstart[node + 1] = beg + excl + c0;
    cnt[l0]     = excl;          // running cursors for scatter phase
    cnt[l0 + 1] = excl + c0;
    __syncthreads();
    for (int i = tid; i < sz; i += 256) {
        u32 v;
        if (i < BCAP) v = ent[i];
        else { int k = (i - BCAP) >> 8; v = (k < OVF) ? ovf[k] : bin[beg + i]; }
        int pos = atomicAdd(&cnt[v >> 18], 1);
        bin[beg + pos] = v & 0x3FFFFu;      // in-place: now holds sorted src (col)
    }
}

// ---------------- mean aggregation ----------------
// One wave per dst node; half-wave = edge parity, 32 lanes = 32 feature-pairs.
// 4-deep unroll per half-wave -> 8 gathers in flight per wave.

template <bool FP32IN>
__global__ __launch_bounds__(256) void agg_kernel(const void* __restrict__ xin,
        const int* __restrict__ rowstart, const int* __restrict__ col,
        u32* __restrict__ out, int n) {
    int node = blockIdx.x * 4 + (threadIdx.x >> 6);
    if (node >= n) return;
    node = __builtin_amdgcn_readfirstlane(node);
    int lane = threadIdx.x & 63;
    int half = lane >> 5;
    int fl   = lane & 31;
    int beg = rowstart[node];
    int dgv = rowstart[node + 1] - beg;
    float a0 = 0.f, a1 = 0.f, b0 = 0.f, b1 = 0.f, c0 = 0.f, c1 = 0.f, d0 = 0.f, d1 = 0.f;
    int j = half;
    if (FP32IN) {
        const float2* xf = (const float2*)xin;
        for (; j + 6 < dgv; j += 8) {
            int s0 = col[beg + j],     s1 = col[beg + j + 2];
            int s2 = col[beg + j + 4], s3 = col[beg + j + 6];
            float2 v0 = xf[s0 * 32 + fl], v1 = xf[s1 * 32 + fl];
            float2 v2 = xf[s2 * 32 + fl], v3 = xf[s3 * 32 + fl];
            a0 += v0.x; a1 += v0.y; b0 += v1.x; b1 += v1.y;
            c0 += v2.x; c1 += v2.y; d0 += v3.x; d1 += v3.y;
        }
        for (; j < dgv; j += 2) {
            float2 v = xf[col[beg + j] * 32 + fl];
            a0 += v.x; a1 += v.y;
        }
    } else {
        const u32* xb = (const u32*)xin;
        for (; j + 6 < dgv; j += 8) {
            int s0 = col[beg + j],     s1 = col[beg + j + 2];
            int s2 = col[beg + j + 4], s3 = col[beg + j + 6];
            u32 p0 = xb[s0 * 32 + fl], p1 = xb[s1 * 32 + fl];
            u32 p2 = xb[s2 * 32 + fl], p3 = xb[s3 * 32 + fl];
            a0 += bf2f((u16)p0); a1 += bf2f((u16)(p0 >> 16));
            b0 += bf2f((u16)p1); b1 += bf2f((u16)(p1 >> 16));
            c0 += bf2f((u16)p2); c1 += bf2f((u16)(p2 >> 16));
            d0 += bf2f((u16)p3); d1 += bf2f((u16)(p3 >> 16));
        }
        for (; j < dgv; j += 2) {
            u32 pv = xb[col[beg + j] * 32 + fl];
            a0 += bf2f((u16)pv); a1 += bf2f((u16)(pv >> 16));
        }
    }
    a0 = (a0 + b0) + (c0 + d0);
    a1 = (a1 + b1) + (c1 + d1);
    a0 += __shfl_xor(a0, 32, 64);
    a1 += __shfl_xor(a1, 32, 64);
    if (half == 0) {
        float inv = __builtin_amdgcn_rcpf((float)(dgv > 1 ? dgv : 1));
        out[node * 32 + fl] = (u32)f2bf(a0 * inv) | ((u32)f2bf(a1 * inv) << 16);
    }
}

// ---------------- user mix: user_emb = W[i] @ [sx(u); tx(u)] + b[i] ----------------
__global__ __launch_bounds__(256) void mix_kernel(u16* __restrict__ sbuf, u16* __restrict__ tbuf,
        const float* __restrict__ w, const float* __restrict__ bias, int nu) {
    __shared__ float wT[128 * 65];     // [k][d], stride 65 -> conflict-free r/w
    int tid = threadIdx.x;
    for (int idx = tid; idx < 8192; idx += 256) {
        int d = idx >> 7, k = idx & 127;          // w[d*128+k], coalesced read
        wT[k * 65 + d] = w[idx];
    }
    __syncthreads();
    int lane = tid & 63;
    int u = blockIdx.x * 4 + (tid >> 6);
    if (u < nu) {
        float cs = bf2f(sbuf[u * 64 + lane]);
        float ct = bf2f(tbuf[u * 64 + lane]);
        float acc = bias[lane];
#pragma unroll
        for (int k = 0; k < 64; ++k) acc += wT[k * 65 + lane] * rdlane(cs, k);
#pragma unroll
        for (int k = 0; k < 64; ++k) acc += wT[(64 + k) * 65 + lane] * rdlane(ct, k);
        u16 r = f2bf(acc);
        sbuf[u * 64 + lane] = r;
        tbuf[u * 64 + lane] = r;
    }
}

// ---------------- predictor: per-layer linear accumulation ----------------

__global__ __launch_bounds__(256) void pred0_kernel(const float* __restrict__ emb,
        const int* __restrict__ l0, const int* __restrict__ l1,
        const float* __restrict__ pw, float* __restrict__ acc, int nl) {
    int li = blockIdx.x * 4 + (threadIdx.x >> 6);
    if (li >= nl) return;
    li = __builtin_amdgcn_readfirstlane(li);
    int lane = threadIdx.x & 63;
    int u = l0[li], v = l1[li];
    float s = pw[lane] * emb[u * 64 + lane] + pw[256 + lane] * emb[v * 64 + lane];
#pragma unroll
    for (int off = 32; off > 0; off >>= 1) s += __shfl_xor(s, off, 64);
    if (lane == 0) acc[li] = s;
}

__global__ __launch_bounds__(256) void predl_kernel(const u16* __restrict__ xb,
        const int* __restrict__ l0, const int* __restrict__ l1,
        const float* __restrict__ pw, int ofA, int ofB,
        float* __restrict__ acc, int nl,
        const float* __restrict__ pb, int finalize, float* __restrict__ out) {
    int li = blockIdx.x * 4 + (threadIdx.x >> 6);
    if (li >= nl) return;
    li = __builtin_amdgcn_readfirstlane(li);
    int lane = threadIdx.x & 63;
    int u = l0[li], v = l1[li];
    float s = pw[ofA + lane] * bf2f(xb[u * 64 + lane])
            + pw[ofB + lane] * bf2f(xb[v * 64 + lane]);
#pragma unroll
    for (int off = 32; off > 0; off >>= 1) s += __shfl_xor(s, off, 64);
    if (lane == 0) {
        float t = acc[li] + s;
        if (finalize) {
            t += pb[0];
            t = t > 0.f ? t : 0.01f * t;
            out[li] = 1.f / (1.f + expf(-t));
        } else {
            acc[li] = t;
        }
    }
}

extern "C" void kernel_launch(void* const* d_in, const int* in_sizes, int n_in,
                              void* d_out, int out_size, void* d_ws, size_t ws_size,
                              hipStream_t stream) {
    const int*   se  = (const int*)d_in[0];   // [2,E] src then dst
    const int*   te  = (const int*)d_in[1];
    const int*   lk  = (const int*)d_in[2];   // [2,NLINK]
    const float* emb = (const float*)d_in[3]; // [N,64]
    const float* mw  = (const float*)d_in[4]; // [3,64,128]
    const float* mb  = (const float*)d_in[5]; // [3,64]
    const float* pw  = (const float*)d_in[6]; // [1,512]
    const float* pb  = (const float*)d_in[7]; // [1]
    float* out = (float*)d_out;

    const int E  = in_sizes[0] / 2;
    const int NL = in_sizes[2] / 2;
    const int N  = in_sizes[3] / 64;
    const int U  = 100000;
    const int NB = (N + BWIDTH - 1) >> BSHIFT;   // 391 coarse buckets

    char* p = (char*)d_ws;
    auto alloc = [&](size_t bytes) -> char* {
        char* r = p;
        p += (bytes + 255) & ~(size_t)255;
        return r;
    };
    u32* A    = (u32*)alloc((size_t)N * 32 * 4);   // bf16 node buf (25.6MB)
    u32* B    = (u32*)alloc((size_t)N * 32 * 4);
    u32* C    = (u32*)alloc((size_t)N * 32 * 4);
    u32* col_s = (u32*)alloc((size_t)E * 4);       // bin -> in-place sorted col
    u32* col_t = (u32*)alloc((size_t)E * 4);
    int* rs_s  = (int*)alloc((size_t)(N + 1) * 4);
    int* rs_t  = (int*)alloc((size_t)(N + 1) * 4);
    float* acc = (float*)alloc((size_t)NL * 4);
    int* gcnt_s = (int*)alloc(BWIDTH * 4);
    int* gcnt_t = (int*)alloc(BWIDTH * 4);
    int* bbase_s = (int*)alloc((BWIDTH + 1) * 4);
    int* bbase_t = (int*)alloc((BWIDTH + 1) * 4);
    int* cur_s = (int*)alloc(BWIDTH * 4);
    int* cur_t = (int*)alloc(BWIDTH * 4);

    hipMemsetAsync(gcnt_s, 0, BWIDTH * 4, stream);
    hipMemsetAsync(gcnt_t, 0, BWIDTH * 4, stream);

    int gB = (E + CHUNK - 1) / CHUNK;
    bucket_hist<<<gB, 256, 0, stream>>>(se + E, E, gcnt_s);
    bucket_hist<<<gB, 256, 0, stream>>>(te + E, E, gcnt_t);
    bucket_scan<<<1, 64, 0, stream>>>(gcnt_s, NB, bbase_s, cur_s, rs_s, N);
    bucket_scan<<<1, 64, 0, stream>>>(gcnt_t, NB, bbase_t, cur_t, rs_t, N);
    bin_kernel<<<gB, 256, 0, stream>>>(se, se + E, E, cur_s, col_s);
    bin_kernel<<<gB, 256, 0, stream>>>(te, te + E, E, cur_t, col_t);
    sort_kernel<<<NB, 256, 0, stream>>>(col_s, bbase_s, rs_s, N);
    sort_kernel<<<NB, 256, 0, stream>>>(col_t, bbase_t, rs_t, N);

    int gagg  = (N + 3) / 4;
    int gmix  = (U + 3) / 4;
    int gpred = (NL + 3) / 4;

    // layer-0 predictor contribution (fp32 emb)
    pred0_kernel<<<gpred, 256, 0, stream>>>(emb, lk, lk + NL, pw, acc, NL);

    // layer 1: A = agg_s(emb), B = agg_t(emb)
    agg_kernel<true ><<<gagg, 256, 0, stream>>>(emb, rs_s, (const int*)col_s, A, N);
    agg_kernel<true ><<<gagg, 256, 0, stream>>>(emb, rs_t, (const int*)col_t, B, N);
    mix_kernel<<<gmix, 256, 0, stream>>>((u16*)A, (u16*)B, mw + 0 * 8192, mb + 0 * 64, U);
    predl_kernel<<<gpred, 256, 0, stream>>>((const u16*)A, lk, lk + NL, pw, 64, 320, acc, NL, pb, 0, out);

    // layer 2: C = agg_s(A), A = agg_t(B)
    agg_kernel<false><<<gagg, 256, 0, stream>>>(A, rs_s, (const int*)col_s, C, N);
    agg_kernel<false><<<gagg, 256, 0, stream>>>(B, rs_t, (const int*)col_t, A, N);
    mix_kernel<<<gmix, 256, 0, stream>>>((u16*)C, (u16*)A, mw + 1 * 8192, mb + 1 * 64, U);
    predl_kernel<<<gpred, 256, 0, stream>>>((const u16*)C, lk, lk + NL, pw, 128, 384, acc, NL, pb, 0, out);

    // layer 3: B = agg_s(C), C = agg_t(A)
    agg_kernel<false><<<gagg, 256, 0, stream>>>(C, rs_s, (const int*)col_s, B, N);
    agg_kernel<false><<<gagg, 256, 0, stream>>>(A, rs_t, (const int*)col_t, C, N);
    mix_kernel<<<gmix, 256, 0, stream>>>((u16*)B, (u16*)C, mw + 2 * 8192, mb + 2 * 64, U);
    predl_kernel<<<gpred, 256, 0, stream>>>((const u16*)B, lk, lk + NL, pw, 192, 448, acc, NL, pb, 1, out);
}

// Round 4
// 922.039 us; speedup vs baseline: 2.3873x; 1.3989x over previous
//
#include <hip/hip_runtime.h>
#include <hip/hip_bf16.h>
#include <math.h>

// N=200000 nodes, U=100000 users, D=64, L=3, E=3,000,000 per edge list, NLINK=100000.
// ws: 3 bf16 node bufs (76.8MB) + 2 bin/col (24MB, sorted in place) + aux ~= 104MB.

typedef unsigned short u16;
typedef unsigned int   u32;
typedef __attribute__((ext_vector_type(8))) short bf16x8;
typedef __attribute__((ext_vector_type(4))) float f32x4;

#define BSHIFT 9                 // 512 nodes per coarse bucket
#define BWIDTH 512
#define BCAP   8192              // LDS staging per sort bucket
#define OVF    8                 // +2048 entries of per-thread register headroom
#define HCHUNK 8192              // edges per hist block
#define BCHUNK 16384             // edges per bin block (longer segments -> fewer random lines)

__device__ __forceinline__ float bf2f(u16 v) {
    u32 x = ((u32)v) << 16;
    return __builtin_bit_cast(float, x);
}
__device__ __forceinline__ u16 f2bf(float f) {
    u32 x = __builtin_bit_cast(u32, f);
    u32 r = x + 0x7fffu + ((x >> 16) & 1u);   // round-to-nearest-even
    return (u16)(r >> 16);
}
__device__ __forceinline__ float flo(u32 p) { return __builtin_bit_cast(float, p << 16); }
__device__ __forceinline__ float fhi(u32 p) { return __builtin_bit_cast(float, p & 0xffff0000u); }
__device__ __forceinline__ int imin(int a, int b) { return a < b ? a : b; }

// ---- D1: fused hist(s) + hist(t) + W->bf16 prep ----
__global__ __launch_bounds__(256) void prep_hist(const int* __restrict__ sdst,
        const int* __restrict__ tdst, int e, int* __restrict__ gcnt2,
        const float* __restrict__ mw, u16* __restrict__ mwb, int nhist) {
    __shared__ int lcnt[BWIDTH];
    int bid = blockIdx.x, tid = threadIdx.x;
    if (bid < 2 * nhist) {
        const int* dst = (bid < nhist) ? sdst : tdst;
        int* gcnt = gcnt2 + ((bid < nhist) ? 0 : BWIDTH);
        int cb = (bid < nhist) ? bid : bid - nhist;
        for (int i = tid; i < BWIDTH; i += 256) lcnt[i] = 0;
        __syncthreads();
        int base = cb * HCHUNK, end = imin(base + HCHUNK, e);
        for (int i = base + tid; i < end; i += 256)
            atomicAdd(&lcnt[(u32)dst[i] >> BSHIFT], 1);
        __syncthreads();
        for (int i = tid; i < BWIDTH; i += 256)
            if (lcnt[i]) atomicAdd(&gcnt[i], lcnt[i]);
    } else {
        int idx = (bid - 2 * nhist) * 256 + tid;
        if (idx < 3 * 64 * 128) mwb[idx] = f2bf(mw[idx]);
    }
}

// ---- D2: fused bucket scans (2 blocks) + pred0 (layer-0 predictor term, fp32 emb) ----
__global__ __launch_bounds__(256) void scan_pred0(const int* __restrict__ gcnt2, int nb,
        int* __restrict__ bbase_s, int* __restrict__ bbase_t, int* __restrict__ cur2,
        int* __restrict__ rs_s, int* __restrict__ rs_t, int n, int e,
        const float* __restrict__ emb, const int* __restrict__ l0, const int* __restrict__ l1,
        const float* __restrict__ pw, float* __restrict__ acc, int nl) {
    int bid = blockIdx.x;
    if (bid < 2) {
        if (threadIdx.x == 0) {
            const int* g = gcnt2 + bid * BWIDTH;
            int* bb = bid ? bbase_t : bbase_s;
            int* cu = cur2 + bid * BWIDTH;
            int* rs = bid ? rs_t : rs_s;
            int run = 0;
            for (int i = 0; i < nb; ++i) { bb[i] = run; cu[i] = run; run += g[i]; }
            bb[nb] = run;
            rs[n] = run;
        }
        return;
    }
    int li = (bid - 2) * 4 + (threadIdx.x >> 6);
    if (li >= nl) return;
    li = __builtin_amdgcn_readfirstlane(li);
    int lane = threadIdx.x & 63;
    int u = l0[li], v = l1[li];
    float s = pw[lane] * emb[(size_t)u * 64 + lane] + pw[256 + lane] * emb[(size_t)v * 64 + lane];
#pragma unroll
    for (int off = 32; off > 0; off >>= 1) s += __shfl_xor(s, off, 64);
    if (lane == 0) acc[li] = s;
}

// ---- D3: fused binning (both lists) ----
__global__ __launch_bounds__(256) void bin2_kernel(const int* __restrict__ ssrc,
        const int* __restrict__ sdst, const int* __restrict__ tsrc, const int* __restrict__ tdst,
        int e, int* __restrict__ cur2, u32* __restrict__ bin_s, u32* __restrict__ bin_t,
        int nbin) {
    __shared__ int lcnt[BWIDTH];
    __shared__ int lbase[BWIDTH];
    int bid = blockIdx.x, tid = threadIdx.x;
    const int* src; const int* dst; int* cursor; u32* bin; int cb;
    if (bid < nbin) { src = ssrc; dst = sdst; cursor = cur2; bin = bin_s; cb = bid; }
    else { src = tsrc; dst = tdst; cursor = cur2 + BWIDTH; bin = bin_t; cb = bid - nbin; }
    for (int i = tid; i < BWIDTH; i += 256) lcnt[i] = 0;
    __syncthreads();
    int base = cb * BCHUNK, end = imin(base + BCHUNK, e);
    for (int i = base + tid; i < end; i += 256)
        atomicAdd(&lcnt[(u32)dst[i] >> BSHIFT], 1);
    __syncthreads();
    for (int i = tid; i < BWIDTH; i += 256) {
        int c = lcnt[i];
        lbase[i] = c ? atomicAdd(&cursor[i], c) : 0;
        lcnt[i] = 0;
    }
    __syncthreads();
    for (int i = base + tid; i < end; i += 256) {
        int d = dst[i];
        int b = (u32)d >> BSHIFT;
        int pos = lbase[b] + atomicAdd(&lcnt[b], 1);
        bin[pos] = (u32)src[i] | ((u32)(d & (BWIDTH - 1)) << 18);   // src < 2^18
    }
}

// ---- D4: fused per-bucket counting sort (both lists), in place ----
__global__ __launch_bounds__(256) void sort2_kernel(u32* __restrict__ bin_s, u32* __restrict__ bin_t,
        const int* __restrict__ bbase_s, const int* __restrict__ bbase_t,
        int* __restrict__ rs_s, int* __restrict__ rs_t, int n, int nb) {
    __shared__ u32 ent[BCAP];
    __shared__ int cnt[BWIDTH];
    __shared__ int part[256];
    int bid = blockIdx.x, tid = threadIdx.x;
    u32* bin; const int* bbase; int* rowstart; int b;
    if (bid < nb) { bin = bin_s; bbase = bbase_s; rowstart = rs_s; b = bid; }
    else { bin = bin_t; bbase = bbase_t; rowstart = rs_t; b = bid - nb; }
    int beg = bbase[b], end = bbase[b + 1];
    int sz = end - beg;
    for (int i = tid; i < BWIDTH; i += 256) cnt[i] = 0;
    __syncthreads();
    u32 ovf[OVF];
    for (int i = tid; i < sz; i += 256) {
        u32 v = bin[beg + i];
        if (i < BCAP) ent[i] = v;
        else { int k = (i - BCAP) >> 8; if (k < OVF) ovf[k] = v; }
        atomicAdd(&cnt[v >> 18], 1);
    }
    __syncthreads();
    int l0 = tid * 2;
    int c0 = cnt[l0], c1 = cnt[l0 + 1];
    int s = c0 + c1;
    part[tid] = s;
    __syncthreads();
    for (int off = 1; off < 256; off <<= 1) {
        int t = (tid >= off) ? part[tid - off] : 0;
        __syncthreads();
        part[tid] += t;
        __syncthreads();
    }
    int excl = part[tid] - s;
    int node = (b << BSHIFT) + l0;
    if (node < n)     rowstart[node]     = beg + excl;
    if (node + 1 < n) rowstart[node + 1] = beg + excl + c0;
    cnt[l0]     = excl;
    cnt[l0 + 1] = excl + c0;
    __syncthreads();
    for (int i = tid; i < sz; i += 256) {
        u32 v;
        if (i < BCAP) v = ent[i];
        else { int k = (i - BCAP) >> 8; v = (k < OVF) ? ovf[k] : bin[beg + i]; }
        int pos = atomicAdd(&cnt[v >> 18], 1);
        bin[beg + pos] = v & 0x3FFFFu;
    }
}

// ---- mean aggregation + optional fused predictor blocks ----
// Agg: one wave per dst node; 16 lanes/edge (8B each), 4 edge groups, 4-deep unroll
// -> 16 gathers in flight per wave. Predicated via clamped index + zero-mask.
template <bool FP32IN>
__global__ __launch_bounds__(256) void aggp_kernel(
        const void* __restrict__ x0, const int* __restrict__ rsA, const u32* __restrict__ colA,
        u32* __restrict__ outA, int nblkA,
        const void* __restrict__ x1, const int* __restrict__ rsB, const u32* __restrict__ colB,
        u32* __restrict__ outB, int nblkB, int n,
        const u16* __restrict__ px, const int* __restrict__ l0, const int* __restrict__ l1,
        const float* __restrict__ pw, int ofA, int ofB, float* __restrict__ acc, int nl,
        int npred) {
    int bid = blockIdx.x;
    int lane = threadIdx.x & 63;
    if (bid < npred) {
        int li = bid * 4 + (threadIdx.x >> 6);
        if (li >= nl) return;
        li = __builtin_amdgcn_readfirstlane(li);
        int u = l0[li], v = l1[li];
        float s = pw[ofA + lane] * bf2f(px[(size_t)u * 64 + lane])
                + pw[ofB + lane] * bf2f(px[(size_t)v * 64 + lane]);
#pragma unroll
        for (int off = 32; off > 0; off >>= 1) s += __shfl_xor(s, off, 64);
        if (lane == 0) acc[li] += s;
        return;
    }
    bid -= npred;
    const void* xin; const int* rs; const u32* col; u32* out;
    if (bid < nblkA) { xin = x0; rs = rsA; col = colA; out = outA; }
    else { bid -= nblkA; xin = x1; rs = rsB; col = colB; out = outB; }
    int node = bid * 4 + (threadIdx.x >> 6);
    if (node >= n) return;
    node = __builtin_amdgcn_readfirstlane(node);
    int g  = lane >> 4;      // edge group
    int fl = lane & 15;      // feature quad (features 4fl..4fl+3)
    int beg = rs[node];
    int dgv = rs[node + 1] - beg;
    int dgm1 = dgv - 1;
    float a0 = 0.f, a1 = 0.f, a2 = 0.f, a3 = 0.f;
    for (int jb = 0; jb < dgv; jb += 16) {
        int j0 = jb + g, j1 = j0 + 4, j2 = j0 + 8, j3 = j0 + 12;
        int s0 = col[beg + imin(j0, dgm1)];
        int s1 = col[beg + imin(j1, dgm1)];
        int s2 = col[beg + imin(j2, dgm1)];
        int s3 = col[beg + imin(j3, dgm1)];
        if (FP32IN) {
            const float4* xf = (const float4*)xin;
            float4 v0 = xf[(size_t)s0 * 16 + fl];
            float4 v1 = xf[(size_t)s1 * 16 + fl];
            float4 v2 = xf[(size_t)s2 * 16 + fl];
            float4 v3 = xf[(size_t)s3 * 16 + fl];
            if (j0 > dgm1) v0.x = v0.y = v0.z = v0.w = 0.f;
            if (j1 > dgm1) v1.x = v1.y = v1.z = v1.w = 0.f;
            if (j2 > dgm1) v2.x = v2.y = v2.z = v2.w = 0.f;
            if (j3 > dgm1) v3.x = v3.y = v3.z = v3.w = 0.f;
            a0 += v0.x + v1.x + v2.x + v3.x;
            a1 += v0.y + v1.y + v2.y + v3.y;
            a2 += v0.z + v1.z + v2.z + v3.z;
            a3 += v0.w + v1.w + v2.w + v3.w;
        } else {
            const uint2* xb = (const uint2*)xin;
            uint2 p0 = xb[(size_t)s0 * 16 + fl];
            uint2 p1 = xb[(size_t)s1 * 16 + fl];
            uint2 p2 = xb[(size_t)s2 * 16 + fl];
            uint2 p3 = xb[(size_t)s3 * 16 + fl];
            if (j0 > dgm1) { p0.x = 0; p0.y = 0; }
            if (j1 > dgm1) { p1.x = 0; p1.y = 0; }
            if (j2 > dgm1) { p2.x = 0; p2.y = 0; }
            if (j3 > dgm1) { p3.x = 0; p3.y = 0; }
            a0 += flo(p0.x) + flo(p1.x) + flo(p2.x) + flo(p3.x);
            a1 += fhi(p0.x) + fhi(p1.x) + fhi(p2.x) + fhi(p3.x);
            a2 += flo(p0.y) + flo(p1.y) + flo(p2.y) + flo(p3.y);
            a3 += fhi(p0.y) + fhi(p1.y) + fhi(p2.y) + fhi(p3.y);
        }
    }
    a0 += __shfl_xor(a0, 16, 64); a0 += __shfl_xor(a0, 32, 64);
    a1 += __shfl_xor(a1, 16, 64); a1 += __shfl_xor(a1, 32, 64);
    a2 += __shfl_xor(a2, 16, 64); a2 += __shfl_xor(a2, 32, 64);
    a3 += __shfl_xor(a3, 16, 64); a3 += __shfl_xor(a3, 32, 64);
    if (g == 0) {
        float inv = __builtin_amdgcn_rcpf((float)(dgv > 1 ? dgv : 1));
        u32 r0 = (u32)f2bf(a0 * inv) | ((u32)f2bf(a1 * inv) << 16);
        u32 r1 = (u32)f2bf(a2 * inv) | ((u32)f2bf(a3 * inv) << 16);
        uint2 r; r.x = r0; r.y = r1;
        ((uint2*)out)[(size_t)node * 16 + fl] = r;
    }
}

// ---- user mix via MFMA: one wave = 16 users, K=128 (sbuf||tbuf), 64 outputs ----
__global__ __launch_bounds__(256) void mix_mfma(u16* __restrict__ sbuf, u16* __restrict__ tbuf,
        const u16* __restrict__ wb /*[64][128] bf16*/, const float* __restrict__ bias, int nu) {
    int lane = threadIdx.x & 63;
    int wv = threadIdx.x >> 6;
    int m = lane & 15, q = lane >> 4;
    int ubase = blockIdx.x * 64 + wv * 16;
    int ul = ubase + m;
    int usafe = ul < nu ? ul : nu - 1;
    const bf16x8* srow = (const bf16x8*)(sbuf + (size_t)usafe * 64);
    const bf16x8* trow = (const bf16x8*)(tbuf + (size_t)usafe * 64);
    bf16x8 a0 = srow[q];        // A[m][k], k = q*8+j   (k 0..31)
    bf16x8 a1 = srow[4 + q];    // k 32..63
    bf16x8 a2 = trow[q];        // k 64..95
    bf16x8 a3 = trow[4 + q];    // k 96..127
    f32x4 accv[4];
#pragma unroll
    for (int t = 0; t < 4; ++t) { accv[t].x = accv[t].y = accv[t].z = accv[t].w = 0.f; }
#pragma unroll
    for (int t = 0; t < 4; ++t) {
        const u16* wd = wb + (size_t)(t * 16 + m) * 128;   // B[k][n]=W[d=n][k], per-lane 16B runs
        accv[t] = __builtin_amdgcn_mfma_f32_16x16x32_bf16(a0, *(const bf16x8*)(wd + q * 8), accv[t], 0, 0, 0);
        accv[t] = __builtin_amdgcn_mfma_f32_16x16x32_bf16(a1, *(const bf16x8*)(wd + 32 + q * 8), accv[t], 0, 0, 0);
        accv[t] = __builtin_amdgcn_mfma_f32_16x16x32_bf16(a2, *(const bf16x8*)(wd + 64 + q * 8), accv[t], 0, 0, 0);
        accv[t] = __builtin_amdgcn_mfma_f32_16x16x32_bf16(a3, *(const bf16x8*)(wd + 96 + q * 8), accv[t], 0, 0, 0);
    }
    // C layout: row(user)=q*4+reg, col(d within tile)=m
    int urow = ubase + q * 4;
#pragma unroll
    for (int t = 0; t < 4; ++t) {
        float bv = bias[t * 16 + m];
#pragma unroll
        for (int r = 0; r < 4; ++r) {
            int uu = urow + r;
            if (uu < nu) {
                u16 h = f2bf(accv[t][r] + bv);
                sbuf[(size_t)uu * 64 + t * 16 + m] = h;
                tbuf[(size_t)uu * 64 + t * 16 + m] = h;
            }
        }
    }
}

// ---- standalone final predictor ----
__global__ __launch_bounds__(256) void predl_kernel(const u16* __restrict__ xb,
        const int* __restrict__ l0, const int* __restrict__ l1,
        const float* __restrict__ pw, int ofA, int ofB,
        float* __restrict__ acc, int nl,
        const float* __restrict__ pb, float* __restrict__ out) {
    int li = blockIdx.x * 4 + (threadIdx.x >> 6);
    if (li >= nl) return;
    li = __builtin_amdgcn_readfirstlane(li);
    int lane = threadIdx.x & 63;
    int u = l0[li], v = l1[li];
    float s = pw[ofA + lane] * bf2f(xb[(size_t)u * 64 + lane])
            + pw[ofB + lane] * bf2f(xb[(size_t)v * 64 + lane]);
#pragma unroll
    for (int off = 32; off > 0; off >>= 1) s += __shfl_xor(s, off, 64);
    if (lane == 0) {
        float t = acc[li] + s + pb[0];
        t = t > 0.f ? t : 0.01f * t;
        out[li] = 1.f / (1.f + expf(-t));
    }
}

extern "C" void kernel_launch(void* const* d_in, const int* in_sizes, int n_in,
                              void* d_out, int out_size, void* d_ws, size_t ws_size,
                              hipStream_t stream) {
    const int*   se  = (const int*)d_in[0];   // [2,E] src then dst
    const int*   te  = (const int*)d_in[1];
    const int*   lk  = (const int*)d_in[2];   // [2,NLINK]
    const float* emb = (const float*)d_in[3]; // [N,64]
    const float* mw  = (const float*)d_in[4]; // [3,64,128]
    const float* mb  = (const float*)d_in[5]; // [3,64]
    const float* pw  = (const float*)d_in[6]; // [1,512]
    const float* pb  = (const float*)d_in[7]; // [1]
    float* out = (float*)d_out;

    const int E  = in_sizes[0] / 2;
    const int NL = in_sizes[2] / 2;
    const int N  = in_sizes[3] / 64;
    const int U  = 100000;
    const int NB = (N + BWIDTH - 1) >> BSHIFT;   // 391

    char* p = (char*)d_ws;
    auto alloc = [&](size_t bytes) -> char* {
        char* r = p;
        p += (bytes + 255) & ~(size_t)255;
        return r;
    };
    u32* A     = (u32*)alloc((size_t)N * 32 * 4);   // bf16 node buf (25.6MB)
    u32* B     = (u32*)alloc((size_t)N * 32 * 4);
    u32* C     = (u32*)alloc((size_t)N * 32 * 4);
    u32* col_s = (u32*)alloc((size_t)E * 4);        // bin -> in-place sorted col
    u32* col_t = (u32*)alloc((size_t)E * 4);
    int* rs_s  = (int*)alloc((size_t)(N + 1) * 4);
    int* rs_t  = (int*)alloc((size_t)(N + 1) * 4);
    float* acc = (float*)alloc((size_t)NL * 4);
    int* gcnt2 = (int*)alloc(2 * BWIDTH * 4);
    int* bbase_s = (int*)alloc((BWIDTH + 1) * 4);
    int* bbase_t = (int*)alloc((BWIDTH + 1) * 4);
    int* cur2  = (int*)alloc(2 * BWIDTH * 4);
    u16* mwb   = (u16*)alloc(3 * 64 * 128 * 2);

    hipMemsetAsync(gcnt2, 0, 2 * BWIDTH * 4, stream);

    const int NHIST = (E + HCHUNK - 1) / HCHUNK;   // 367
    const int NBIN  = (E + BCHUNK - 1) / BCHUNK;   // 184
    const int GA    = (N + 3) / 4;                 // 50000 agg blocks per list
    const int GP    = (NL + 3) / 4;                // 25000 pred blocks
    const int GM    = (U + 63) / 64;               // 1563 mix blocks

    // D1: hist both + W prep
    prep_hist<<<2 * NHIST + 96, 256, 0, stream>>>(se + E, te + E, E, gcnt2, mw, mwb, NHIST);
    // D2: bucket scans + pred0
    scan_pred0<<<2 + GP, 256, 0, stream>>>(gcnt2, NB, bbase_s, bbase_t, cur2, rs_s, rs_t,
                                           N, E, emb, lk, lk + NL, pw, acc, NL);
    // D3: bin both
    bin2_kernel<<<2 * NBIN, 256, 0, stream>>>(se, se + E, te, te + E, E, cur2, col_s, col_t, NBIN);
    // D4: sort both
    sort2_kernel<<<2 * NB, 256, 0, stream>>>(col_s, col_t, bbase_s, bbase_t, rs_s, rs_t, N, NB);

    // D5: layer-1 agg, both lists from fp32 emb -> A (s), B (t)
    aggp_kernel<true><<<2 * GA, 256, 0, stream>>>(
        emb, rs_s, col_s, A, GA, emb, rs_t, col_t, B, GA, N,
        (const u16*)nullptr, nullptr, nullptr, nullptr, 0, 0, nullptr, 0, 0);
    // D6: mix1 (A,B user rows)
    mix_mfma<<<GM, 256, 0, stream>>>((u16*)A, (u16*)B, mwb + 0 * 8192, mb + 0 * 64, U);
    // D7: predl1(A) + agg_s L2: A -> C
    aggp_kernel<false><<<GP + GA, 256, 0, stream>>>(
        A, rs_s, col_s, C, GA, nullptr, nullptr, nullptr, nullptr, 0, N,
        (const u16*)A, lk, lk + NL, pw, 64, 320, acc, NL, GP);
    // D8: agg_t L2: B -> A
    aggp_kernel<false><<<GA, 256, 0, stream>>>(
        B, rs_t, col_t, A, GA, nullptr, nullptr, nullptr, nullptr, 0, N,
        (const u16*)nullptr, nullptr, nullptr, nullptr, 0, 0, nullptr, 0, 0);
    // D9: mix2 (C = s-chain, A = t-chain)
    mix_mfma<<<GM, 256, 0, stream>>>((u16*)C, (u16*)A, mwb + 1 * 8192, mb + 1 * 64, U);
    // D10: predl2(C) + agg_s L3: C -> B
    aggp_kernel<false><<<GP + GA, 256, 0, stream>>>(
        C, rs_s, col_s, B, GA, nullptr, nullptr, nullptr, nullptr, 0, N,
        (const u16*)C, lk, lk + NL, pw, 128, 384, acc, NL, GP);
    // D11: agg_t L3: A -> C
    aggp_kernel<false><<<GA, 256, 0, stream>>>(
        A, rs_t, col_t, C, GA, nullptr, nullptr, nullptr, nullptr, 0, N,
        (const u16*)nullptr, nullptr, nullptr, nullptr, 0, 0, nullptr, 0, 0);
    // D12: mix3 (B = s-chain, C = t-chain)
    mix_mfma<<<GM, 256, 0, stream>>>((u16*)B, (u16*)C, mwb + 2 * 8192, mb + 2 * 64, U);
    // D13: final predictor on B (s-chain L3)
    predl_kernel<<<GP, 256, 0, stream>>>((const u16*)B, lk, lk + NL, pw, 192, 448, acc, NL, pb, out);
}

// Round 5
// 822.573 us; speedup vs baseline: 2.6760x; 1.1209x over previous
//
#include <hip/hip_runtime.h>
#include <hip/hip_bf16.h>
#include <math.h>

// N=200000 nodes, U=100000 users, D=64, L=3, E=3,000,000 per edge list, NLINK=100000.
// ws: 3 bf16 node bufs (76.8MB) + 2 bin/col (24MB, sorted in place) + aux ~= 104MB.

typedef unsigned short u16;
typedef unsigned int   u32;
typedef __attribute__((ext_vector_type(8))) short bf16x8;
typedef __attribute__((ext_vector_type(4))) float f32x4;

#define BSHIFT 9                 // 512 nodes per coarse bucket
#define BWIDTH 512
#define BCAP   8192              // LDS staging per sort bucket
#define OVF    8                 // +2048 entries of per-thread register headroom
#define HCHUNK 8192              // edges per hist block
#define BCHUNK 16384             // edges per bin block

__device__ __forceinline__ float bf2f(u16 v) {
    u32 x = ((u32)v) << 16;
    return __builtin_bit_cast(float, x);
}
__device__ __forceinline__ u16 f2bf(float f) {
    u32 x = __builtin_bit_cast(u32, f);
    u32 r = x + 0x7fffu + ((x >> 16) & 1u);   // round-to-nearest-even
    return (u16)(r >> 16);
}
__device__ __forceinline__ u32 pack2(float a, float b) {
    return (u32)f2bf(a) | ((u32)f2bf(b) << 16);
}
__device__ __forceinline__ float flo(u32 p) { return __builtin_bit_cast(float, p << 16); }
__device__ __forceinline__ float fhi(u32 p) { return __builtin_bit_cast(float, p & 0xffff0000u); }
__device__ __forceinline__ int imin(int a, int b) { return a < b ? a : b; }

// ---- D1: fused hist(s) + hist(t) + W->bf16 prep + emb->bf16 staging ----
__global__ __launch_bounds__(256) void prep_hist(const int* __restrict__ sdst,
        const int* __restrict__ tdst, int e, int* __restrict__ gcnt2,
        const float* __restrict__ mw, u16* __restrict__ mwb,
        const float* __restrict__ emb, u32* __restrict__ embb, int nelem,
        int nhist, int nwprep) {
    __shared__ int lcnt[BWIDTH];
    int bid = blockIdx.x, tid = threadIdx.x;
    if (bid < 2 * nhist) {
        const int* dst = (bid < nhist) ? sdst : tdst;
        int* gcnt = gcnt2 + ((bid < nhist) ? 0 : BWIDTH);
        int cb = (bid < nhist) ? bid : bid - nhist;
        for (int i = tid; i < BWIDTH; i += 256) lcnt[i] = 0;
        __syncthreads();
        int base = cb * HCHUNK, end = imin(base + HCHUNK, e);
        for (int i = base + tid; i < end; i += 256)
            atomicAdd(&lcnt[(u32)dst[i] >> BSHIFT], 1);
        __syncthreads();
        for (int i = tid; i < BWIDTH; i += 256)
            if (lcnt[i]) atomicAdd(&gcnt[i], lcnt[i]);
    } else if (bid < 2 * nhist + nwprep) {
        int idx = (bid - 2 * nhist) * 256 + tid;
        if (idx < 3 * 64 * 128) mwb[idx] = f2bf(mw[idx]);
    } else {
        int idx = (bid - 2 * nhist - nwprep) * 1024 + tid * 4;   // 4 floats / thread
        if (idx < nelem) {
            float4 v = *(const float4*)(emb + idx);
            uint2 r;
            r.x = pack2(v.x, v.y);
            r.y = pack2(v.z, v.w);
            *(uint2*)(embb + (idx >> 1)) = r;
        }
    }
}

// ---- D2: parallel bucket scans (2 blocks) + pred0 (layer-0 term, fp32 emb) ----
__global__ __launch_bounds__(256) void scan_pred0(const int* __restrict__ gcnt2, int nb,
        int* __restrict__ bbase_s, int* __restrict__ bbase_t, int* __restrict__ cur2,
        int* __restrict__ rs_s, int* __restrict__ rs_t, int n,
        const float* __restrict__ emb, const int* __restrict__ l0, const int* __restrict__ l1,
        const float* __restrict__ pw, float* __restrict__ acc, int nl) {
    int bid = blockIdx.x;
    int tid = threadIdx.x;
    if (bid < 2) {
        __shared__ int part[256];
        const int* g = gcnt2 + bid * BWIDTH;
        int* bb = bid ? bbase_t : bbase_s;
        int* cu = cur2 + bid * BWIDTH;
        int* rs = bid ? rs_t : rs_s;
        int i0 = tid * 2;
        int c0 = g[i0], c1 = g[i0 + 1];          // zero beyond nb (memset + hist-only)
        int s = c0 + c1;
        part[tid] = s;
        __syncthreads();
        for (int off = 1; off < 256; off <<= 1) {
            int t = (tid >= off) ? part[tid - off] : 0;
            __syncthreads();
            part[tid] += t;
            __syncthreads();
        }
        int excl = part[tid] - s;
        if (i0 <= nb)     { bb[i0] = excl; }
        if (i0 + 1 <= nb) { bb[i0 + 1] = excl + c0; }
        if (i0 < nb)      cu[i0] = excl;
        if (i0 + 1 < nb)  cu[i0 + 1] = excl + c0;
        if (tid == 255)   rs[n] = part[255];
        return;
    }
    int li = (bid - 2) * 4 + (tid >> 6);
    if (li >= nl) return;
    li = __builtin_amdgcn_readfirstlane(li);
    int lane = tid & 63;
    int u = l0[li], v = l1[li];
    float s = pw[lane] * emb[(size_t)u * 64 + lane] + pw[256 + lane] * emb[(size_t)v * 64 + lane];
#pragma unroll
    for (int off = 32; off > 0; off >>= 1) s += __shfl_xor(s, off, 64);
    if (lane == 0) acc[li] = s;
}

// ---- D3: fused binning (both lists) ----
__global__ __launch_bounds__(256) void bin2_kernel(const int* __restrict__ ssrc,
        const int* __restrict__ sdst, const int* __restrict__ tsrc, const int* __restrict__ tdst,
        int e, int* __restrict__ cur2, u32* __restrict__ bin_s, u32* __restrict__ bin_t,
        int nbin) {
    __shared__ int lcnt[BWIDTH];
    __shared__ int lbase[BWIDTH];
    int bid = blockIdx.x, tid = threadIdx.x;
    const int* src; const int* dst; int* cursor; u32* bin; int cb;
    if (bid < nbin) { src = ssrc; dst = sdst; cursor = cur2; bin = bin_s; cb = bid; }
    else { src = tsrc; dst = tdst; cursor = cur2 + BWIDTH; bin = bin_t; cb = bid - nbin; }
    for (int i = tid; i < BWIDTH; i += 256) lcnt[i] = 0;
    __syncthreads();
    int base = cb * BCHUNK, end = imin(base + BCHUNK, e);
    for (int i = base + tid; i < end; i += 256)
        atomicAdd(&lcnt[(u32)dst[i] >> BSHIFT], 1);
    __syncthreads();
    for (int i = tid; i < BWIDTH; i += 256) {
        int c = lcnt[i];
        lbase[i] = c ? atomicAdd(&cursor[i], c) : 0;
        lcnt[i] = 0;
    }
    __syncthreads();
    for (int i = base + tid; i < end; i += 256) {
        int d = dst[i];
        int b = (u32)d >> BSHIFT;
        int pos = lbase[b] + atomicAdd(&lcnt[b], 1);
        bin[pos] = (u32)src[i] | ((u32)(d & (BWIDTH - 1)) << 18);   // src < 2^18
    }
}

// ---- D4: fused per-bucket counting sort (both lists), in place ----
__global__ __launch_bounds__(256) void sort2_kernel(u32* __restrict__ bin_s, u32* __restrict__ bin_t,
        const int* __restrict__ bbase_s, const int* __restrict__ bbase_t,
        int* __restrict__ rs_s, int* __restrict__ rs_t, int n, int nb) {
    __shared__ u32 ent[BCAP];
    __shared__ int cnt[BWIDTH];
    __shared__ int part[256];
    int bid = blockIdx.x, tid = threadIdx.x;
    u32* bin; const int* bbase; int* rowstart; int b;
    if (bid < nb) { bin = bin_s; bbase = bbase_s; rowstart = rs_s; b = bid; }
    else { bin = bin_t; bbase = bbase_t; rowstart = rs_t; b = bid - nb; }
    int beg = bbase[b], end = bbase[b + 1];
    int sz = end - beg;
    for (int i = tid; i < BWIDTH; i += 256) cnt[i] = 0;
    __syncthreads();
    u32 ovf[OVF];
    for (int i = tid; i < sz; i += 256) {
        u32 v = bin[beg + i];
        if (i < BCAP) ent[i] = v;
        else { int k = (i - BCAP) >> 8; if (k < OVF) ovf[k] = v; }
        atomicAdd(&cnt[v >> 18], 1);
    }
    __syncthreads();
    int l0 = tid * 2;
    int c0 = cnt[l0], c1 = cnt[l0 + 1];
    int s = c0 + c1;
    part[tid] = s;
    __syncthreads();
    for (int off = 1; off < 256; off <<= 1) {
        int t = (tid >= off) ? part[tid - off] : 0;
        __syncthreads();
        part[tid] += t;
        __syncthreads();
    }
    int excl = part[tid] - s;
    int node = (b << BSHIFT) + l0;
    if (node < n)     rowstart[node]     = beg + excl;
    if (node + 1 < n) rowstart[node + 1] = beg + excl + c0;
    cnt[l0]     = excl;
    cnt[l0 + 1] = excl + c0;
    __syncthreads();
    for (int i = tid; i < sz; i += 256) {
        u32 v;
        if (i < BCAP) v = ent[i];
        else { int k = (i - BCAP) >> 8; v = (k < OVF) ? ovf[k] : bin[beg + i]; }
        int pos = atomicAdd(&cnt[v >> 18], 1);
        bin[beg + pos] = v & 0x3FFFFu;
    }
}

// ---- mean aggregation (bf16 in/out) + optional fused predictor blocks ----
// One wave per dst node; 16 lanes/edge (8B each), 4 edge groups, 4-deep unroll.
__global__ __launch_bounds__(256) void aggp_kernel(
        const u32* __restrict__ x0, const int* __restrict__ rsA, const u32* __restrict__ colA,
        u32* __restrict__ outA, int nblkA,
        const u32* __restrict__ x1, const int* __restrict__ rsB, const u32* __restrict__ colB,
        u32* __restrict__ outB, int nblkB, int n,
        const u16* __restrict__ px, const int* __restrict__ l0, const int* __restrict__ l1,
        const float* __restrict__ pw, int ofA, int ofB, float* __restrict__ acc, int nl,
        int npred) {
    int bid = blockIdx.x;
    int lane = threadIdx.x & 63;
    if (bid < npred) {
        int li = bid * 4 + (threadIdx.x >> 6);
        if (li >= nl) return;
        li = __builtin_amdgcn_readfirstlane(li);
        int u = l0[li], v = l1[li];
        float s = pw[ofA + lane] * bf2f(px[(size_t)u * 64 + lane])
                + pw[ofB + lane] * bf2f(px[(size_t)v * 64 + lane]);
#pragma unroll
        for (int off = 32; off > 0; off >>= 1) s += __shfl_xor(s, off, 64);
        if (lane == 0) acc[li] += s;
        return;
    }
    bid -= npred;
    const u32* xin; const int* rs; const u32* col; u32* out;
    if (bid < nblkA) { xin = x0; rs = rsA; col = colA; out = outA; }
    else { bid -= nblkA; xin = x1; rs = rsB; col = colB; out = outB; }
    int node = bid * 4 + (threadIdx.x >> 6);
    if (node >= n) return;
    node = __builtin_amdgcn_readfirstlane(node);
    int g  = lane >> 4;      // edge group
    int fl = lane & 15;      // feature quad (features 4fl..4fl+3)
    int beg = rs[node];
    int dgv = rs[node + 1] - beg;
    int dgm1 = dgv - 1;
    float a0 = 0.f, a1 = 0.f, a2 = 0.f, a3 = 0.f;
    const uint2* xb = (const uint2*)xin;
    for (int jb = 0; jb < dgv; jb += 16) {
        int j0 = jb + g, j1 = j0 + 4, j2 = j0 + 8, j3 = j0 + 12;
        int s0 = col[beg + imin(j0, dgm1)];
        int s1 = col[beg + imin(j1, dgm1)];
        int s2 = col[beg + imin(j2, dgm1)];
        int s3 = col[beg + imin(j3, dgm1)];
        uint2 p0 = xb[(size_t)s0 * 16 + fl];
        uint2 p1 = xb[(size_t)s1 * 16 + fl];
        uint2 p2 = xb[(size_t)s2 * 16 + fl];
        uint2 p3 = xb[(size_t)s3 * 16 + fl];
        if (j0 > dgm1) { p0.x = 0; p0.y = 0; }
        if (j1 > dgm1) { p1.x = 0; p1.y = 0; }
        if (j2 > dgm1) { p2.x = 0; p2.y = 0; }
        if (j3 > dgm1) { p3.x = 0; p3.y = 0; }
        a0 += flo(p0.x) + flo(p1.x) + flo(p2.x) + flo(p3.x);
        a1 += fhi(p0.x) + fhi(p1.x) + fhi(p2.x) + fhi(p3.x);
        a2 += flo(p0.y) + flo(p1.y) + flo(p2.y) + flo(p3.y);
        a3 += fhi(p0.y) + fhi(p1.y) + fhi(p2.y) + fhi(p3.y);
    }
    a0 += __shfl_xor(a0, 16, 64); a0 += __shfl_xor(a0, 32, 64);
    a1 += __shfl_xor(a1, 16, 64); a1 += __shfl_xor(a1, 32, 64);
    a2 += __shfl_xor(a2, 16, 64); a2 += __shfl_xor(a2, 32, 64);
    a3 += __shfl_xor(a3, 16, 64); a3 += __shfl_xor(a3, 32, 64);
    if (g == 0) {
        float inv = __builtin_amdgcn_rcpf((float)(dgv > 1 ? dgv : 1));
        uint2 r;
        r.x = pack2(a0 * inv, a1 * inv);
        r.y = pack2(a2 * inv, a3 * inv);
        ((uint2*)out)[(size_t)node * 16 + fl] = r;
    }
}

// ---- user mix via MFMA: one wave = 16 users, K=128 (sbuf||tbuf), 64 outputs ----
__global__ __launch_bounds__(256) void mix_mfma(u16* __restrict__ sbuf, u16* __restrict__ tbuf,
        const u16* __restrict__ wb /*[64][128] bf16*/, const float* __restrict__ bias, int nu) {
    int lane = threadIdx.x & 63;
    int wv = threadIdx.x >> 6;
    int m = lane & 15, q = lane >> 4;
    int ubase = blockIdx.x * 64 + wv * 16;
    int ul = ubase + m;
    int usafe = ul < nu ? ul : nu - 1;
    const bf16x8* srow = (const bf16x8*)(sbuf + (size_t)usafe * 64);
    const bf16x8* trow = (const bf16x8*)(tbuf + (size_t)usafe * 64);
    bf16x8 a0 = srow[q];
    bf16x8 a1 = srow[4 + q];
    bf16x8 a2 = trow[q];
    bf16x8 a3 = trow[4 + q];
    f32x4 accv[4];
#pragma unroll
    for (int t = 0; t < 4; ++t) { accv[t].x = accv[t].y = accv[t].z = accv[t].w = 0.f; }
#pragma unroll
    for (int t = 0; t < 4; ++t) {
        const u16* wd = wb + (size_t)(t * 16 + m) * 128;
        accv[t] = __builtin_amdgcn_mfma_f32_16x16x32_bf16(a0, *(const bf16x8*)(wd + q * 8), accv[t], 0, 0, 0);
        accv[t] = __builtin_amdgcn_mfma_f32_16x16x32_bf16(a1, *(const bf16x8*)(wd + 32 + q * 8), accv[t], 0, 0, 0);
        accv[t] = __builtin_amdgcn_mfma_f32_16x16x32_bf16(a2, *(const bf16x8*)(wd + 64 + q * 8), accv[t], 0, 0, 0);
        accv[t] = __builtin_amdgcn_mfma_f32_16x16x32_bf16(a3, *(const bf16x8*)(wd + 96 + q * 8), accv[t], 0, 0, 0);
    }
    int urow = ubase + q * 4;
#pragma unroll
    for (int t = 0; t < 4; ++t) {
        float bv = bias[t * 16 + m];
#pragma unroll
        for (int r = 0; r < 4; ++r) {
            int uu = urow + r;
            if (uu < nu) {
                u16 h = f2bf(accv[t][r] + bv);
                sbuf[(size_t)uu * 64 + t * 16 + m] = h;
                tbuf[(size_t)uu * 64 + t * 16 + m] = h;
            }
        }
    }
}

// ---- standalone final predictor ----
__global__ __launch_bounds__(256) void predl_kernel(const u16* __restrict__ xb,
        const int* __restrict__ l0, const int* __restrict__ l1,
        const float* __restrict__ pw, int ofA, int ofB,
        float* __restrict__ acc, int nl,
        const float* __restrict__ pb, float* __restrict__ out) {
    int li = blockIdx.x * 4 + (threadIdx.x >> 6);
    if (li >= nl) return;
    li = __builtin_amdgcn_readfirstlane(li);
    int lane = threadIdx.x & 63;
    int u = l0[li], v = l1[li];
    float s = pw[ofA + lane] * bf2f(xb[(size_t)u * 64 + lane])
            + pw[ofB + lane] * bf2f(xb[(size_t)v * 64 + lane]);
#pragma unroll
    for (int off = 32; off > 0; off >>= 1) s += __shfl_xor(s, off, 64);
    if (lane == 0) {
        float t = acc[li] + s + pb[0];
        t = t > 0.f ? t : 0.01f * t;
        out[li] = 1.f / (1.f + expf(-t));
    }
}

extern "C" void kernel_launch(void* const* d_in, const int* in_sizes, int n_in,
                              void* d_out, int out_size, void* d_ws, size_t ws_size,
                              hipStream_t stream) {
    const int*   se  = (const int*)d_in[0];   // [2,E] src then dst
    const int*   te  = (const int*)d_in[1];
    const int*   lk  = (const int*)d_in[2];   // [2,NLINK]
    const float* emb = (const float*)d_in[3]; // [N,64]
    const float* mw  = (const float*)d_in[4]; // [3,64,128]
    const float* mb  = (const float*)d_in[5]; // [3,64]
    const float* pw  = (const float*)d_in[6]; // [1,512]
    const float* pb  = (const float*)d_in[7]; // [1]
    float* out = (float*)d_out;

    const int E  = in_sizes[0] / 2;
    const int NL = in_sizes[2] / 2;
    const int N  = in_sizes[3] / 64;
    const int U  = 100000;
    const int NB = (N + BWIDTH - 1) >> BSHIFT;   // 391

    char* p = (char*)d_ws;
    auto alloc = [&](size_t bytes) -> char* {
        char* r = p;
        p += (bytes + 255) & ~(size_t)255;
        return r;
    };
    u32* A     = (u32*)alloc((size_t)N * 32 * 4);   // bf16 node buf (25.6MB)
    u32* B     = (u32*)alloc((size_t)N * 32 * 4);
    u32* C     = (u32*)alloc((size_t)N * 32 * 4);   // D1: bf16(emb); later t-chain/s-chain
    u32* col_s = (u32*)alloc((size_t)E * 4);        // bin -> in-place sorted col
    u32* col_t = (u32*)alloc((size_t)E * 4);
    int* rs_s  = (int*)alloc((size_t)(N + 1) * 4);
    int* rs_t  = (int*)alloc((size_t)(N + 1) * 4);
    float* acc = (float*)alloc((size_t)NL * 4);
    int* gcnt2 = (int*)alloc(2 * BWIDTH * 4);
    int* bbase_s = (int*)alloc((BWIDTH + 1) * 4);
    int* bbase_t = (int*)alloc((BWIDTH + 1) * 4);
    int* cur2  = (int*)alloc(2 * BWIDTH * 4);
    u16* mwb   = (u16*)alloc(3 * 64 * 128 * 2);

    hipMemsetAsync(gcnt2, 0, 2 * BWIDTH * 4, stream);

    const int NHIST = (E + HCHUNK - 1) / HCHUNK;     // 367
    const int NBIN  = (E + BCHUNK - 1) / BCHUNK;     // 184
    const int NWPREP = 96;
    const int NCONV = (N * 64 + 1023) / 1024;        // 12500
    const int GA    = (N + 3) / 4;                   // 50000
    const int GAU   = (U + 3) / 4;                   // 25000 (layer-3 t-agg: users only)
    const int GP    = (NL + 3) / 4;                  // 25000
    const int GM    = (U + 63) / 64;                 // 1563

    // D1: hist both + W prep + emb->bf16 into C
    prep_hist<<<2 * NHIST + NWPREP + NCONV, 256, 0, stream>>>(
        se + E, te + E, E, gcnt2, mw, mwb, emb, C, N * 64, NHIST, NWPREP);
    // D2: parallel bucket scans + pred0
    scan_pred0<<<2 + GP, 256, 0, stream>>>(gcnt2, NB, bbase_s, bbase_t, cur2, rs_s, rs_t,
                                           N, emb, lk, lk + NL, pw, acc, NL);
    // D3: bin both
    bin2_kernel<<<2 * NBIN, 256, 0, stream>>>(se, se + E, te, te + E, E, cur2, col_s, col_t, NBIN);
    // D4: sort both
    sort2_kernel<<<2 * NB, 256, 0, stream>>>(col_s, col_t, bbase_s, bbase_t, rs_s, rs_t, N, NB);

    // D5: layer-1 agg, both lists from bf16(emb)=C -> A (s), B (t)
    aggp_kernel<<<2 * GA, 256, 0, stream>>>(
        C, rs_s, col_s, A, GA, C, rs_t, col_t, B, GA, N,
        (const u16*)nullptr, nullptr, nullptr, nullptr, 0, 0, nullptr, 0, 0);
    // D6: mix1 (A,B user rows)
    mix_mfma<<<GM, 256, 0, stream>>>((u16*)A, (u16*)B, mwb + 0 * 8192, mb + 0 * 64, U);
    // D7: predl1(A) + agg_s L2: A -> C
    aggp_kernel<<<GP + GA, 256, 0, stream>>>(
        A, rs_s, col_s, C, GA, nullptr, nullptr, nullptr, nullptr, 0, N,
        (const u16*)A, lk, lk + NL, pw, 64, 320, acc, NL, GP);
    // D8: agg_t L2: B -> A
    aggp_kernel<<<GA, 256, 0, stream>>>(
        B, rs_t, col_t, A, GA, nullptr, nullptr, nullptr, nullptr, 0, N,
        (const u16*)nullptr, nullptr, nullptr, nullptr, 0, 0, nullptr, 0, 0);
    // D9: mix2 (C = s-chain, A = t-chain)
    mix_mfma<<<GM, 256, 0, stream>>>((u16*)C, (u16*)A, mwb + 1 * 8192, mb + 1 * 64, U);
    // D10: predl2(C) + agg_s L3: C -> B
    aggp_kernel<<<GP + GA, 256, 0, stream>>>(
        C, rs_s, col_s, B, GA, nullptr, nullptr, nullptr, nullptr, 0, N,
        (const u16*)C, lk, lk + NL, pw, 128, 384, acc, NL, GP);
    // D11: agg_t L3 (USER dst rows only): A -> C
    aggp_kernel<<<GAU, 256, 0, stream>>>(
        A, rs_t, col_t, C, GAU, nullptr, nullptr, nullptr, nullptr, 0, U,
        (const u16*)nullptr, nullptr, nullptr, nullptr, 0, 0, nullptr, 0, 0);
    // D12: mix3 (B = s-chain, C = t-chain users)
    mix_mfma<<<GM, 256, 0, stream>>>((u16*)B, (u16*)C, mwb + 2 * 8192, mb + 2 * 64, U);
    // D13: final predictor on B (s-chain L3)
    predl_kernel<<<GP, 256, 0, stream>>>((const u16*)B, lk, lk + NL, pw, 192, 448, acc, NL, pb, out);
}